// Round 2
// baseline (538.121 us; speedup 1.0000x reference)
//
#include <hip/hip_runtime.h>
#include <hip/hip_bf16.h>
#include <cstdint>
#include <cstddef>

typedef __bf16 bf16_t;
typedef __bf16 bf16x8 __attribute__((ext_vector_type(8)));
typedef float f32x4 __attribute__((ext_vector_type(4)));

#define AS1(p) ((const __attribute__((address_space(1))) void*)(p))
#define AS3(p) ((__attribute__((address_space(3))) void*)(p))

// ---------------- cast f32 -> bf16, x4 vectorized ----------------
struct bf16x4_s { bf16_t x, y, z, w; };

__global__ __launch_bounds__(256) void k_cast_bf16(const float4* __restrict__ in,
                                                   bf16x4_s* __restrict__ out, int n4) {
  int i = blockIdx.x * 256 + threadIdx.x;
  if (i < n4) {
    float4 v = in[i];
    bf16x4_s o;
    o.x = (bf16_t)v.x; o.y = (bf16_t)v.y; o.z = (bf16_t)v.z; o.w = (bf16_t)v.w;
    out[i] = o;
  }
}

// -------- (masked) transpose f32 [K][N] -> bf16 [N][K] --------
// comp may be null; mask value = comp[k][n>>3]
__global__ __launch_bounds__(256) void k_transpose(const float* __restrict__ W,
                                                   const int* __restrict__ comp,
                                                   bf16_t* __restrict__ Bt,
                                                   int K, int N, int Pc) {
  __shared__ float tile[64][65];
  const int k0 = blockIdx.x * 64;
  const int n0 = blockIdx.y * 64;
  const int t = threadIdx.x;
  const int c = t & 63;      // lane
  const int r0 = t >> 6;     // wave
#pragma unroll
  for (int i = 0; i < 16; ++i) {
    int r = r0 + i * 4;
    float v = W[(size_t)(k0 + r) * N + n0 + c];
    if (comp) v *= (float)comp[(size_t)(k0 + r) * Pc + ((n0 + c) >> 3)];
    tile[r][c] = v;
  }
  __syncthreads();
#pragma unroll
  for (int i = 0; i < 16; ++i) {
    int r = r0 + i * 4;
    Bt[(size_t)(n0 + r) * K + k0 + c] = (bf16_t)tile[c][r];
  }
}

// ---------------- bf16 MFMA GEMM: C = A[M][K] * Bt[N][K]^T + bias ----------------
// m97-style: 2-barrier K-loop, global_load_lds width 16, 16x16x32 bf16 MFMA.
template<int MI, int NI, bool RELU, typename OT>
__global__ __launch_bounds__(256, 2) void k_gemm(const bf16_t* __restrict__ A,
                                                 const bf16_t* __restrict__ Bt,
                                                 const float* __restrict__ bias,
                                                 OT* __restrict__ C,
                                                 int M, int N, int K) {
  constexpr int BM = MI * 32;   // 2 waves along M
  constexpr int BN = NI * 32;   // 2 waves along N
  constexpr int BK = 32;
  __shared__ bf16_t As[BM][BK];
  __shared__ bf16_t Bs[BN][BK];
  const int tid = threadIdx.x;
  const int wave = tid >> 6;
  const int lane = tid & 63;
  const int m0 = blockIdx.y * BM;
  const int n0 = blockIdx.x * BN;
  const int wm = (wave >> 1) * (MI * 16);
  const int wn = (wave & 1) * (NI * 16);
  const int lrow = lane >> 2;          // staging: row within 16-row chunk
  const int lk = (lane & 3) * 8;       // staging: k element offset
  const int fr = lane & 15;            // fragment row/col
  const int fkb = (lane >> 4) * 8;     // fragment k offset

  f32x4 acc[MI][NI] = {};

  const int nkt = K / BK;
  for (int kt = 0; kt < nkt; ++kt) {
    const int k0 = kt * BK;
    // stage A tile: each global_load_lds iteration covers 16 rows (64 lanes x 16B)
    for (int i = wave; i < BM / 16; i += 4) {
      const bf16_t* g = A + (size_t)(m0 + i * 16 + lrow) * K + k0 + lk;
      __builtin_amdgcn_global_load_lds(AS1(g), AS3(&As[i * 16][0]), 16, 0, 0);
    }
    for (int i = wave; i < BN / 16; i += 4) {
      const bf16_t* g = Bt + (size_t)(n0 + i * 16 + lrow) * K + k0 + lk;
      __builtin_amdgcn_global_load_lds(AS1(g), AS3(&Bs[i * 16][0]), 16, 0, 0);
    }
    __syncthreads();   // compiler emits vmcnt(0) drain before barrier

    bf16x8 af[MI], bfr[NI];
#pragma unroll
    for (int mi = 0; mi < MI; ++mi)
      af[mi] = *reinterpret_cast<const bf16x8*>(&As[wm + mi * 16 + fr][fkb]);
#pragma unroll
    for (int ni = 0; ni < NI; ++ni)
      bfr[ni] = *reinterpret_cast<const bf16x8*>(&Bs[wn + ni * 16 + fr][fkb]);
#pragma unroll
    for (int mi = 0; mi < MI; ++mi)
#pragma unroll
      for (int ni = 0; ni < NI; ++ni)
        acc[mi][ni] = __builtin_amdgcn_mfma_f32_16x16x32_bf16(af[mi], bfr[ni], acc[mi][ni], 0, 0, 0);
    __syncthreads();
  }

  // epilogue: C/D layout col=lane&15, row=(lane>>4)*4+reg  [verified m89/m91]
  const int fq = lane >> 4;
#pragma unroll
  for (int mi = 0; mi < MI; ++mi) {
#pragma unroll
    for (int ni = 0; ni < NI; ++ni) {
      const int col = n0 + wn + ni * 16 + fr;
      const float bb = bias[col];
#pragma unroll
      for (int j = 0; j < 4; ++j) {
        const int row = m0 + wm + mi * 16 + fq * 4 + j;
        float v = acc[mi][ni][j] + bb;
        if (RELU) v = fmaxf(v, 0.0f);
        C[(size_t)row * N + col] = (OT)v;
      }
    }
  }
}

// ---------------- block-diagonal fc2: out2[b, p*16+d2] = sum_d1 out1[b,p*8+d1]*W2[p*8+d1, p*16+d2] + b2 ----------------
__global__ __launch_bounds__(256) void k_fc2(const bf16_t* __restrict__ out1,
                                             const float* __restrict__ W2,
                                             const float* __restrict__ b2,
                                             bf16_t* __restrict__ out2) {
  const int idx = blockIdx.x * 256 + threadIdx.x;  // b*8192 + j
  const int b = idx >> 13;
  const int j = idx & 8191;
  const int p = j >> 4;
  float s = b2[j];
#pragma unroll
  for (int d1 = 0; d1 < 8; ++d1) {
    float a = (float)out1[(size_t)b * 4096 + p * 8 + d1];
    s += a * W2[(size_t)(p * 8 + d1) * 8192 + j];
  }
  out2[idx] = (bf16_t)s;
}

// ---------------- head: logits[b][n] = sum_k h[b][k]*W4[k][n] + b4[n] ----------------
__global__ __launch_bounds__(256) void k_head(const bf16_t* __restrict__ h,
                                              const float* __restrict__ W4,
                                              const float* __restrict__ b4,
                                              float* __restrict__ out) {
  const int b = blockIdx.x;
  const int n = threadIdx.x >> 6;   // wave -> class
  const int lane = threadIdx.x & 63;
  float s = 0.f;
  for (int k = lane; k < 2048; k += 64)
    s += (float)h[(size_t)b * 2048 + k] * W4[k * 4 + n];
#pragma unroll
  for (int off = 32; off; off >>= 1) s += __shfl_down(s, off);
  if (lane == 0) out[b * 4 + n] = s + b4[n];
}

extern "C" void kernel_launch(void* const* d_in, const int* in_sizes, int n_in,
                              void* d_out, int out_size, void* d_ws, size_t ws_size,
                              hipStream_t stream) {
  const float* data  = (const float*)d_in[0];   // [1024][4096]
  const int*   comp  = (const int*)d_in[1];     // [4096][512]
  const float* fc1_w = (const float*)d_in[2];   // [4096][4096]
  const float* fc1_b = (const float*)d_in[3];   // [4096]
  const float* fc2_w = (const float*)d_in[4];   // [4096][8192]
  const float* fc2_b = (const float*)d_in[5];   // [8192]
  const float* w3    = (const float*)d_in[6];   // [8192][2048]
  const float* b3    = (const float*)d_in[7];   // [2048]
  const float* w4    = (const float*)d_in[8];   // [2048][4]
  const float* b4    = (const float*)d_in[9];   // [4]
  float* logits = (float*)d_out;                // [1024][4]

  char* ws = (char*)d_ws;
  bf16_t* dataB = (bf16_t*)(ws);                 // 1024*4096*2  =  8,388,608
  bf16_t* BtBuf = (bf16_t*)(ws + 8388608);       // 4096*4096*2  = 33,554,432 (Bt1, later Bt3)
  bf16_t* out1  = (bf16_t*)(ws + 41943040);      // 1024*4096*2  =  8,388,608
  bf16_t* out2  = (bf16_t*)(ws + 50331648);      // 1024*8192*2  = 16,777,216
  bf16_t* hbuf  = (bf16_t*)(ws + 67108864);      // 1024*2048*2  =  4,194,304
  // total 71,303,168 bytes

  // 1) data -> bf16
  k_cast_bf16<<<4096, 256, 0, stream>>>((const float4*)data, (bf16x4_s*)dataB, 1048576);
  // 2) Bt1[n][k] = bf16(fc1_w[k][n] * comp[k][n>>3])
  k_transpose<<<dim3(64, 64), 256, 0, stream>>>(fc1_w, comp, BtBuf, 4096, 4096, 512);
  // 3) out1 = data @ W1m + b1   (M=1024 N=4096 K=4096)
  k_gemm<4, 4, false, bf16_t><<<dim3(32, 8), 256, 0, stream>>>(dataB, BtBuf, fc1_b, out1, 1024, 4096, 4096);
  // 4) out2 = block-diag fc2
  k_fc2<<<32768, 256, 0, stream>>>(out1, fc2_w, fc2_b, out2);
  // 5) Bt3[n][k] = bf16(w3[k][n])   (reuses BtBuf; stream-ordered after GEMM1)
  k_transpose<<<dim3(128, 32), 256, 0, stream>>>(w3, nullptr, BtBuf, 8192, 2048, 0);
  // 6) h = relu(out2 @ w3 + b3)   (M=1024 N=2048 K=8192)
  k_gemm<2, 4, true, bf16_t><<<dim3(16, 16), 256, 0, stream>>>(out2, BtBuf, b3, hbuf, 1024, 2048, 8192);
  // 7) logits
  k_head<<<1024, 256, 0, stream>>>(hbuf, w4, b4, logits);
}

// Round 3
// 458.528 us; speedup vs baseline: 1.1736x; 1.1736x over previous
//
#include <hip/hip_runtime.h>
#include <hip/hip_bf16.h>
#include <cstdint>
#include <cstddef>

typedef __bf16 bf16_t;
typedef __bf16 bf16x8 __attribute__((ext_vector_type(8)));
typedef float f32x4 __attribute__((ext_vector_type(4)));

#define AS1(p) ((const __attribute__((address_space(1))) void*)(p))
#define AS3(p) ((__attribute__((address_space(3))) void*)(p))

struct bf16x4_s { bf16_t x, y, z, w; };

// -------- masked transpose f32 [K][N] -> bf16 [N][K] (mask = comp[k][n>>3]) --------
__global__ __launch_bounds__(256) void k_transpose(const float* __restrict__ W,
                                                   const int* __restrict__ comp,
                                                   bf16_t* __restrict__ Bt,
                                                   int K, int N, int Pc) {
  __shared__ float tile[64][65];
  const int k0 = blockIdx.x * 64;
  const int n0 = blockIdx.y * 64;
  const int t = threadIdx.x;
  const int c = t & 63;
  const int r0 = t >> 6;
#pragma unroll
  for (int i = 0; i < 16; ++i) {
    int r = r0 + i * 4;
    float v = W[(size_t)(k0 + r) * N + n0 + c];
    v *= (float)comp[(size_t)(k0 + r) * Pc + ((n0 + c) >> 3)];
    tile[r][c] = v;
  }
  __syncthreads();
#pragma unroll
  for (int i = 0; i < 16; ++i) {
    int r = r0 + i * 4;
    Bt[(size_t)(n0 + r) * K + k0 + c] = (bf16_t)tile[c][r];
  }
}

// -------- W23 builder: W23t[n][k] = sum_d2 fc2w[k][p*16+d2]*w3[p*16+d2][n], p=k/8 --------
// Also b23[n] += sum_k2 b2[k2]*w3[k2][n] (atomic partial per pathway-block).
__global__ __launch_bounds__(256) void k_w23(const float* __restrict__ fc2w,
                                             const float* __restrict__ w3,
                                             const float* __restrict__ b2,
                                             bf16_t* __restrict__ W23t,
                                             float* __restrict__ b23) {
  __shared__ float w3s[128][65];
  const int n0 = blockIdx.x * 64;   // 32 n-blocks
  const int pb = blockIdx.y * 8;    // 64 pathway-blocks (8 pathways each)
  const int tid = threadIdx.x;
  const int c = tid & 63, q = tid >> 6;
  // load 128 w3 rows (8 pathways x 16) x 64 cols
#pragma unroll
  for (int i = 0; i < 32; ++i) {
    int rr = i * 4 + q;
    w3s[rr][c] = w3[(size_t)(pb * 16 + rr) * 2048 + n0 + c];
  }
  __syncthreads();
  const int pp = c >> 3;            // local pathway 0..7
  const int k1 = pb * 8 + c;        // global row of W23
  const int p = pb + pp;
  float f2[16];
  const float4* frp = (const float4*)(fc2w + (size_t)k1 * 8192 + (size_t)p * 16);
#pragma unroll
  for (int t4 = 0; t4 < 4; ++t4) {
    float4 v = frp[t4];
    f2[t4 * 4 + 0] = v.x; f2[t4 * 4 + 1] = v.y; f2[t4 * 4 + 2] = v.z; f2[t4 * 4 + 3] = v.w;
  }
#pragma unroll
  for (int i = 0; i < 16; ++i) {
    int nn = i * 4 + q;
    float s = 0.f;
#pragma unroll
    for (int d2 = 0; d2 < 16; ++d2) {
      int d2r = (d2 + 2 * pp) & 15;   // bank-derotated read order
      s += f2[d2r] * w3s[pp * 16 + d2r][nn];
    }
    W23t[(size_t)(n0 + nn) * 4096 + k1] = (bf16_t)s;
  }
  // bias partial: quarter q covers rows q*32..q*32+31 for col c
  float bp = 0.f;
  for (int rr = q * 32; rr < q * 32 + 32; ++rr)
    bp += b2[pb * 16 + rr] * w3s[rr][c];
  atomicAdd(&b23[n0 + c], bp);
}

// -------- split-K MFMA GEMM: P[z] = A[M][K] * Bt[N][K]^T over k-slice z --------
template<int MI, int NI, bool AF32>
__global__ __launch_bounds__(256, 2) void k_gemm_sk(const void* __restrict__ Av,
                                                    const bf16_t* __restrict__ Bt,
                                                    float* __restrict__ P,
                                                    int M, int N, int K, int ksub) {
  constexpr int BM = MI * 32;
  constexpr int BN = NI * 32;
  constexpr int BK = 32;
  __shared__ bf16_t As[BM][BK];
  __shared__ bf16_t Bs[BN][BK];
  const int tid = threadIdx.x;
  const int wave = tid >> 6;
  const int lane = tid & 63;
  const int m0 = blockIdx.y * BM;
  const int n0 = blockIdx.x * BN;
  const int kbase = blockIdx.z * ksub;
  const int wm = (wave >> 1) * (MI * 16);
  const int wn = (wave & 1) * (NI * 16);
  const int lrow = lane >> 2;
  const int lk = (lane & 3) * 8;
  const int fr = lane & 15;
  const int fkb = (lane >> 4) * 8;

  f32x4 acc[MI][NI] = {};
  const int nkt = ksub / BK;
  for (int kt = 0; kt < nkt; ++kt) {
    const int k0 = kbase + kt * BK;
    if constexpr (AF32) {
      const float* Af = (const float*)Av;
      for (int i = wave; i < BM / 16; i += 4) {
        const float* g = Af + (size_t)(m0 + i * 16 + lrow) * K + k0 + lk;
        float4 a0 = *(const float4*)g;
        float4 a1 = *(const float4*)(g + 4);
        bf16x8 v;
        v[0] = (bf16_t)a0.x; v[1] = (bf16_t)a0.y; v[2] = (bf16_t)a0.z; v[3] = (bf16_t)a0.w;
        v[4] = (bf16_t)a1.x; v[5] = (bf16_t)a1.y; v[6] = (bf16_t)a1.z; v[7] = (bf16_t)a1.w;
        *reinterpret_cast<bf16x8*>(&As[i * 16 + lrow][lk]) = v;
      }
    } else {
      const bf16_t* Ab = (const bf16_t*)Av;
      for (int i = wave; i < BM / 16; i += 4) {
        const bf16_t* g = Ab + (size_t)(m0 + i * 16 + lrow) * K + k0 + lk;
        __builtin_amdgcn_global_load_lds(AS1(g), AS3(&As[i * 16][0]), 16, 0, 0);
      }
    }
    for (int i = wave; i < BN / 16; i += 4) {
      const bf16_t* g = Bt + (size_t)(n0 + i * 16 + lrow) * K + k0 + lk;
      __builtin_amdgcn_global_load_lds(AS1(g), AS3(&Bs[i * 16][0]), 16, 0, 0);
    }
    __syncthreads();

    bf16x8 af[MI], bfr[NI];
#pragma unroll
    for (int mi = 0; mi < MI; ++mi)
      af[mi] = *reinterpret_cast<const bf16x8*>(&As[wm + mi * 16 + fr][fkb]);
#pragma unroll
    for (int ni = 0; ni < NI; ++ni)
      bfr[ni] = *reinterpret_cast<const bf16x8*>(&Bs[wn + ni * 16 + fr][fkb]);
#pragma unroll
    for (int mi = 0; mi < MI; ++mi)
#pragma unroll
      for (int ni = 0; ni < NI; ++ni)
        acc[mi][ni] = __builtin_amdgcn_mfma_f32_16x16x32_bf16(af[mi], bfr[ni], acc[mi][ni], 0, 0, 0);
    __syncthreads();
  }

  float* Po = P + (size_t)blockIdx.z * ((size_t)M * N);
  const int fq = lane >> 4;
#pragma unroll
  for (int mi = 0; mi < MI; ++mi)
#pragma unroll
    for (int ni = 0; ni < NI; ++ni) {
      const int col = n0 + wn + ni * 16 + fr;
#pragma unroll
      for (int j = 0; j < 4; ++j) {
        const int row = m0 + wm + mi * 16 + fq * 4 + j;
        Po[(size_t)row * N + col] = acc[mi][ni][j];
      }
    }
}

// -------- reduce split-K partials + bias (+bias2) (+relu) -> bf16 --------
template<int S, bool RELU, bool B2>
__global__ __launch_bounds__(256) void k_reduce(const float* __restrict__ P, size_t sz,
                                                const float* __restrict__ bias1,
                                                const float* __restrict__ bias2,
                                                bf16_t* __restrict__ out, int N) {
  const size_t i = (size_t)blockIdx.x * 256 + threadIdx.x;
  const size_t off = i * 4;
  float4 a = *(const float4*)(P + off);
#pragma unroll
  for (int s = 1; s < S; ++s) {
    float4 t = *(const float4*)(P + (size_t)s * sz + off);
    a.x += t.x; a.y += t.y; a.z += t.z; a.w += t.w;
  }
  const int col = (int)(off & (size_t)(N - 1));
  const float4 b1 = *(const float4*)(bias1 + col);
  a.x += b1.x; a.y += b1.y; a.z += b1.z; a.w += b1.w;
  if (B2) {
    const float4 b2v = *(const float4*)(bias2 + col);
    a.x += b2v.x; a.y += b2v.y; a.z += b2v.z; a.w += b2v.w;
  }
  if (RELU) {
    a.x = fmaxf(a.x, 0.f); a.y = fmaxf(a.y, 0.f);
    a.z = fmaxf(a.z, 0.f); a.w = fmaxf(a.w, 0.f);
  }
  bf16x4_s o{(bf16_t)a.x, (bf16_t)a.y, (bf16_t)a.z, (bf16_t)a.w};
  reinterpret_cast<bf16x4_s*>(out)[i] = o;
}

// -------- head: logits[b][n] = sum_k h[b][k]*W4[k][n] + b4[n] --------
__global__ __launch_bounds__(256) void k_head(const bf16_t* __restrict__ h,
                                              const float* __restrict__ W4,
                                              const float* __restrict__ b4,
                                              float* __restrict__ out) {
  const int b = blockIdx.x;
  const int n = threadIdx.x >> 6;
  const int lane = threadIdx.x & 63;
  float s = 0.f;
  for (int k = lane; k < 2048; k += 64)
    s += (float)h[(size_t)b * 2048 + k] * W4[k * 4 + n];
#pragma unroll
  for (int off = 32; off; off >>= 1) s += __shfl_down(s, off);
  if (lane == 0) out[b * 4 + n] = s + b4[n];
}

extern "C" void kernel_launch(void* const* d_in, const int* in_sizes, int n_in,
                              void* d_out, int out_size, void* d_ws, size_t ws_size,
                              hipStream_t stream) {
  const float* data  = (const float*)d_in[0];   // [1024][4096] fp32
  const int*   comp  = (const int*)d_in[1];     // [4096][512]
  const float* fc1_w = (const float*)d_in[2];   // [4096][4096]
  const float* fc1_b = (const float*)d_in[3];   // [4096]
  const float* fc2_w = (const float*)d_in[4];   // [4096][8192]
  const float* fc2_b = (const float*)d_in[5];   // [8192]
  const float* w3    = (const float*)d_in[6];   // [8192][2048]
  const float* b3    = (const float*)d_in[7];   // [2048]
  const float* w4    = (const float*)d_in[8];   // [2048][4]
  const float* b4    = (const float*)d_in[9];   // [4]
  float* logits = (float*)d_out;                // [1024][4]

  char* ws = (char*)d_ws;
  // Phase A (through GEMM1): Bt1 @ [0,32M), P @ [32M,64M)
  // Phase B (after GEMM1):   out1 @ [0,8M), W23t @ [8M,24M), b23 @ 24M, hbuf @ 24M+8K, P reused
  bf16_t* Bt1  = (bf16_t*)(ws);                  // 33,554,432
  bf16_t* out1 = (bf16_t*)(ws);                  //  8,388,608 (over dead Bt1)
  bf16_t* W23t = (bf16_t*)(ws + 8388608);        // 16,777,216
  float*  b23  = (float*)(ws + 25165824);        //      8,192
  bf16_t* hbuf = (bf16_t*)(ws + 25174016);       //  4,194,304
  float*  P    = (float*)(ws + 33554432);        // 33,554,432 (both GEMMs' partials)

  // 1) Bt1[n][k] = bf16(fc1_w[k][n] * comp[k][n>>3])
  k_transpose<<<dim3(64, 64), 256, 0, stream>>>(fc1_w, comp, Bt1, 4096, 4096, 512);
  // 2) GEMM1 split-2: P = data(fp32) @ Bt1^T   (M=1024 N=4096 K=4096)
  k_gemm_sk<4, 4, true><<<dim3(32, 8, 2), 256, 0, stream>>>(data, Bt1, P, 1024, 4096, 4096, 2048);
  // 3) out1 = bf16(P0+P1 + fc1_b)
  k_reduce<2, false, false><<<4096, 256, 0, stream>>>(P, (size_t)1024 * 4096, fc1_b, nullptr, out1, 4096);
  // 4) b23 = 0; then W23t + b23 partials
  hipMemsetAsync(b23, 0, 8192, stream);
  k_w23<<<dim3(32, 64), 256, 0, stream>>>(fc2_w, w3, fc2_b, W23t, b23);
  // 5) GEMM2 split-4: P = out1 @ W23t^T   (M=1024 N=2048 K=4096)
  k_gemm_sk<4, 4, false><<<dim3(16, 8, 4), 256, 0, stream>>>(out1, W23t, P, 1024, 2048, 4096, 1024);
  // 6) hbuf = bf16(relu(sum P + b23 + b3))
  k_reduce<4, true, true><<<2048, 256, 0, stream>>>(P, (size_t)1024 * 2048, b23, b3, hbuf, 2048);
  // 7) logits
  k_head<<<1024, 256, 0, stream>>>(hbuf, w4, b4, logits);
}

// Round 5
// 400.667 us; speedup vs baseline: 1.3431x; 1.1444x over previous
//
#include <hip/hip_runtime.h>
#include <hip/hip_bf16.h>
#include <cstdint>
#include <cstddef>

typedef __bf16 bf16_t;
typedef __bf16 bf16x8 __attribute__((ext_vector_type(8)));
typedef float f32x4 __attribute__((ext_vector_type(4)));

#define AS1(p) ((const __attribute__((address_space(1))) void*)(p))
#define AS3(p) ((__attribute__((address_space(3))) void*)(p))

struct bf16x4_s { bf16_t x, y, z, w; };

// ---------------- cast f32 -> bf16, x4 vectorized ----------------
__global__ __launch_bounds__(256) void k_cast_bf16(const float4* __restrict__ in,
                                                   bf16x4_s* __restrict__ out, int n4) {
  int i = blockIdx.x * 256 + threadIdx.x;
  if (i < n4) {
    float4 v = in[i];
    bf16x4_s o{(bf16_t)v.x, (bf16_t)v.y, (bf16_t)v.z, (bf16_t)v.w};
    out[i] = o;
  }
}

// -------- masked transpose f32 [K][N] -> bf16 [N][K] (mask = comp[k][n>>3]) --------
__global__ __launch_bounds__(256) void k_transpose(const float* __restrict__ W,
                                                   const int* __restrict__ comp,
                                                   bf16_t* __restrict__ Bt,
                                                   int K, int N, int Pc) {
  __shared__ float tile[64][65];
  const int k0 = blockIdx.x * 64;
  const int n0 = blockIdx.y * 64;
  const int t = threadIdx.x;
  const int c = t & 63;
  const int r0 = t >> 6;
#pragma unroll
  for (int i = 0; i < 16; ++i) {
    int r = r0 + i * 4;
    float v = W[(size_t)(k0 + r) * N + n0 + c];
    v *= (float)comp[(size_t)(k0 + r) * Pc + ((n0 + c) >> 3)];
    tile[r][c] = v;
  }
  __syncthreads();
#pragma unroll
  for (int i = 0; i < 16; ++i) {
    int r = r0 + i * 4;
    Bt[(size_t)(n0 + r) * K + k0 + c] = (bf16_t)tile[c][r];
  }
}

// -------- W23 builder: W23t[n][k] = sum_d2 fc2w[k][p*16+d2]*w3[p*16+d2][n], p=k/8 --------
__global__ __launch_bounds__(256) void k_w23(const float* __restrict__ fc2w,
                                             const float* __restrict__ w3,
                                             const float* __restrict__ b2,
                                             bf16_t* __restrict__ W23t,
                                             float* __restrict__ b23) {
  __shared__ float w3s[128][65];
  const int n0 = blockIdx.x * 64;
  const int pb = blockIdx.y * 8;
  const int tid = threadIdx.x;
  const int c = tid & 63, q = tid >> 6;
#pragma unroll
  for (int i = 0; i < 32; ++i) {
    int rr = i * 4 + q;
    w3s[rr][c] = w3[(size_t)(pb * 16 + rr) * 2048 + n0 + c];
  }
  __syncthreads();
  const int pp = c >> 3;
  const int k1 = pb * 8 + c;
  const int p = pb + pp;
  float f2[16];
  const float4* frp = (const float4*)(fc2w + (size_t)k1 * 8192 + (size_t)p * 16);
#pragma unroll
  for (int t4 = 0; t4 < 4; ++t4) {
    float4 v = frp[t4];
    f2[t4 * 4 + 0] = v.x; f2[t4 * 4 + 1] = v.y; f2[t4 * 4 + 2] = v.z; f2[t4 * 4 + 3] = v.w;
  }
#pragma unroll
  for (int i = 0; i < 16; ++i) {
    int nn = i * 4 + q;
    float s = 0.f;
#pragma unroll
    for (int d2 = 0; d2 < 16; ++d2) {
      int d2r = (d2 + 2 * pp) & 15;
      s += f2[d2r] * w3s[pp * 16 + d2r][nn];
    }
    W23t[(size_t)(n0 + nn) * 4096 + k1] = (bf16_t)s;
  }
  float bp = 0.f;
  for (int rr = q * 32; rr < q * 32 + 32; ++rr)
    bp += b2[pb * 16 + rr] * w3s[rr][c];
  atomicAdd(&b23[n0 + c], bp);
}

// -------- split-K MFMA GEMM, 2-phase double-buffered (T3 minimum recipe) --------
template<int MI, int NI, bool AF32>
__global__ __launch_bounds__(256, AF32 ? 2 : 4)
void k_gemm_sk(const void* __restrict__ Av,
               const bf16_t* __restrict__ Bt,
               float* __restrict__ P,
               int M, int N, int K, int ksub) {
  constexpr int BM = MI * 32, BN = NI * 32, BK = 32;
  constexpr int AIT = BM / 64;   // per-wave A stage iterations
  constexpr int BIT = BN / 64;
  __shared__ bf16_t As[2][BM][BK];
  __shared__ bf16_t Bs[2][BN][BK];
  const int tid = threadIdx.x, wave = tid >> 6, lane = tid & 63;
  const int m0 = blockIdx.y * BM, n0 = blockIdx.x * BN;
  const int kbase = blockIdx.z * ksub;
  const int wm = (wave >> 1) * (MI * 16), wn = (wave & 1) * (NI * 16);
  const int lrow = lane >> 2, lk = (lane & 3) * 8;
  const int fr = lane & 15, fkb = (lane >> 4) * 8;
  const float* Af = (const float*)Av;
  const bf16_t* Ab = (const bf16_t*)Av;

  f32x4 acc[MI][NI] = {};
  const int nkt = ksub / BK;

  // prologue: stage tile 0 into buf 0
  if constexpr (AF32) {
#pragma unroll
    for (int ii = 0; ii < AIT; ++ii) {
      const int i = wave + ii * 4;
      const float* g = Af + (size_t)(m0 + i * 16 + lrow) * K + kbase + lk;
      float4 x = *(const float4*)g, y = *(const float4*)(g + 4);
      bf16x8 v;
      v[0] = (bf16_t)x.x; v[1] = (bf16_t)x.y; v[2] = (bf16_t)x.z; v[3] = (bf16_t)x.w;
      v[4] = (bf16_t)y.x; v[5] = (bf16_t)y.y; v[6] = (bf16_t)y.z; v[7] = (bf16_t)y.w;
      *reinterpret_cast<bf16x8*>(&As[0][i * 16 + lrow][lk]) = v;
    }
  } else {
#pragma unroll
    for (int ii = 0; ii < AIT; ++ii) {
      const int i = wave + ii * 4;
      const bf16_t* g = Ab + (size_t)(m0 + i * 16 + lrow) * K + kbase + lk;
      __builtin_amdgcn_global_load_lds(AS1(g), AS3(&As[0][i * 16][0]), 16, 0, 0);
    }
  }
#pragma unroll
  for (int ii = 0; ii < BIT; ++ii) {
    const int i = wave + ii * 4;
    const bf16_t* g = Bt + (size_t)(n0 + i * 16 + lrow) * K + kbase + lk;
    __builtin_amdgcn_global_load_lds(AS1(g), AS3(&Bs[0][i * 16][0]), 16, 0, 0);
  }
  __syncthreads();

  int cur = 0;
  for (int kt = 0; kt < nkt; ++kt) {
    const bool pf = (kt + 1 < nkt);
    const int k1 = kbase + (kt + 1) * BK;
    float4 ax[AIT], ay[AIT];
    if (pf) {
      // issue next-tile loads BEFORE compute (overlap latency with MFMA)
      if constexpr (AF32) {
#pragma unroll
        for (int ii = 0; ii < AIT; ++ii) {
          const int i = wave + ii * 4;
          const float* g = Af + (size_t)(m0 + i * 16 + lrow) * K + k1 + lk;
          ax[ii] = *(const float4*)g;
          ay[ii] = *(const float4*)(g + 4);
        }
      } else {
#pragma unroll
        for (int ii = 0; ii < AIT; ++ii) {
          const int i = wave + ii * 4;
          const bf16_t* g = Ab + (size_t)(m0 + i * 16 + lrow) * K + k1 + lk;
          __builtin_amdgcn_global_load_lds(AS1(g), AS3(&As[cur ^ 1][i * 16][0]), 16, 0, 0);
        }
      }
#pragma unroll
      for (int ii = 0; ii < BIT; ++ii) {
        const int i = wave + ii * 4;
        const bf16_t* g = Bt + (size_t)(n0 + i * 16 + lrow) * K + k1 + lk;
        __builtin_amdgcn_global_load_lds(AS1(g), AS3(&Bs[cur ^ 1][i * 16][0]), 16, 0, 0);
      }
    }

    bf16x8 af[MI], bfr[NI];
#pragma unroll
    for (int mi = 0; mi < MI; ++mi)
      af[mi] = *reinterpret_cast<const bf16x8*>(&As[cur][wm + mi * 16 + fr][fkb]);
#pragma unroll
    for (int ni = 0; ni < NI; ++ni)
      bfr[ni] = *reinterpret_cast<const bf16x8*>(&Bs[cur][wn + ni * 16 + fr][fkb]);
    __builtin_amdgcn_s_setprio(1);
#pragma unroll
    for (int mi = 0; mi < MI; ++mi)
#pragma unroll
      for (int ni = 0; ni < NI; ++ni)
        acc[mi][ni] = __builtin_amdgcn_mfma_f32_16x16x32_bf16(af[mi], bfr[ni], acc[mi][ni], 0, 0, 0);
    __builtin_amdgcn_s_setprio(0);

    if (pf) {
      if constexpr (AF32) {
        // write-late half of T14 split: cvt + ds_write after compute
#pragma unroll
        for (int ii = 0; ii < AIT; ++ii) {
          const int i = wave + ii * 4;
          bf16x8 v;
          v[0] = (bf16_t)ax[ii].x; v[1] = (bf16_t)ax[ii].y; v[2] = (bf16_t)ax[ii].z; v[3] = (bf16_t)ax[ii].w;
          v[4] = (bf16_t)ay[ii].x; v[5] = (bf16_t)ay[ii].y; v[6] = (bf16_t)ay[ii].z; v[7] = (bf16_t)ay[ii].w;
          *reinterpret_cast<bf16x8*>(&As[cur ^ 1][i * 16 + lrow][lk]) = v;
        }
      }
    }
    __syncthreads();
    cur ^= 1;
  }

  float* Po = P + (size_t)blockIdx.z * ((size_t)M * N);
  const int fq = lane >> 4;
#pragma unroll
  for (int mi = 0; mi < MI; ++mi)
#pragma unroll
    for (int ni = 0; ni < NI; ++ni) {
      const int col = n0 + wn + ni * 16 + fr;
#pragma unroll
      for (int j = 0; j < 4; ++j) {
        const int row = m0 + wm + mi * 16 + fq * 4 + j;
        Po[(size_t)row * N + col] = acc[mi][ni][j];
      }
    }
}

// -------- reduce split-K partials + bias (+bias2) (+relu) -> bf16 --------
template<int S, bool RELU, bool B2>
__global__ __launch_bounds__(256) void k_reduce(const float* __restrict__ P, size_t sz,
                                                const float* __restrict__ bias1,
                                                const float* __restrict__ bias2,
                                                bf16_t* __restrict__ out, int N) {
  const size_t i = (size_t)blockIdx.x * 256 + threadIdx.x;
  const size_t off = i * 4;
  float4 a = *(const float4*)(P + off);
#pragma unroll
  for (int s = 1; s < S; ++s) {
    float4 t = *(const float4*)(P + (size_t)s * sz + off);
    a.x += t.x; a.y += t.y; a.z += t.z; a.w += t.w;
  }
  const int col = (int)(off & (size_t)(N - 1));
  const float4 b1 = *(const float4*)(bias1 + col);
  a.x += b1.x; a.y += b1.y; a.z += b1.z; a.w += b1.w;
  if (B2) {
    const float4 b2v = *(const float4*)(bias2 + col);
    a.x += b2v.x; a.y += b2v.y; a.z += b2v.z; a.w += b2v.w;
  }
  if (RELU) {
    a.x = fmaxf(a.x, 0.f); a.y = fmaxf(a.y, 0.f);
    a.z = fmaxf(a.z, 0.f); a.w = fmaxf(a.w, 0.f);
  }
  bf16x4_s o{(bf16_t)a.x, (bf16_t)a.y, (bf16_t)a.z, (bf16_t)a.w};
  reinterpret_cast<bf16x4_s*>(out)[i] = o;
}

// -------- head --------
__global__ __launch_bounds__(256) void k_head(const bf16_t* __restrict__ h,
                                              const float* __restrict__ W4,
                                              const float* __restrict__ b4,
                                              float* __restrict__ out) {
  const int b = blockIdx.x;
  const int n = threadIdx.x >> 6;
  const int lane = threadIdx.x & 63;
  float s = 0.f;
  for (int k = lane; k < 2048; k += 64)
    s += (float)h[(size_t)b * 2048 + k] * W4[k * 4 + n];
#pragma unroll
  for (int off = 32; off; off >>= 1) s += __shfl_down(s, off);
  if (lane == 0) out[b * 4 + n] = s + b4[n];
}

extern "C" void kernel_launch(void* const* d_in, const int* in_sizes, int n_in,
                              void* d_out, int out_size, void* d_ws, size_t ws_size,
                              hipStream_t stream) {
  const float* data  = (const float*)d_in[0];
  const int*   comp  = (const int*)d_in[1];
  const float* fc1_w = (const float*)d_in[2];
  const float* fc1_b = (const float*)d_in[3];
  const float* fc2_w = (const float*)d_in[4];
  const float* fc2_b = (const float*)d_in[5];
  const float* w3    = (const float*)d_in[6];
  const float* b3    = (const float*)d_in[7];
  const float* w4    = (const float*)d_in[8];
  const float* b4    = (const float*)d_in[9];
  float* logits = (float*)d_out;

  char* ws = (char*)d_ws;
  const size_t MB = 1024 * 1024;
  const bool big = ws_size >= 104 * MB;

  if (big) {
    // dataB[0,8M) Bt1[8M,40M) P[40M,104M); phase B: out1[0,8M) W23t[8M,24M) b23@24M hbuf@24M+64K
    bf16_t* dataB = (bf16_t*)(ws);
    bf16_t* Bt1   = (bf16_t*)(ws + 8 * MB);
    float*  P     = (float*)(ws + 40 * MB);
    bf16_t* out1  = (bf16_t*)(ws);
    bf16_t* W23t  = (bf16_t*)(ws + 8 * MB);
    float*  b23   = (float*)(ws + 24 * MB);
    bf16_t* hbuf  = (bf16_t*)(ws + 24 * MB + 65536);

    k_cast_bf16<<<4096, 256, 0, stream>>>((const float4*)data, (bf16x4_s*)dataB, 1048576);
    k_transpose<<<dim3(64, 64), 256, 0, stream>>>(fc1_w, comp, Bt1, 4096, 4096, 512);
    k_gemm_sk<4, 4, false><<<dim3(32, 8, 4), 256, 0, stream>>>(dataB, Bt1, P, 1024, 4096, 4096, 1024);
    k_reduce<4, false, false><<<4096, 256, 0, stream>>>(P, (size_t)1024 * 4096, fc1_b, nullptr, out1, 4096);
    hipMemsetAsync(b23, 0, 8192, stream);
    k_w23<<<dim3(32, 64), 256, 0, stream>>>(fc2_w, w3, fc2_b, W23t, b23);
    k_gemm_sk<4, 4, false><<<dim3(16, 8, 8), 256, 0, stream>>>(out1, W23t, P, 1024, 2048, 4096, 512);
    k_reduce<8, true, true><<<2048, 256, 0, stream>>>(P, (size_t)1024 * 2048, b23, b3, hbuf, 2048);
    k_head<<<1024, 256, 0, stream>>>(hbuf, w4, b4, logits);
  } else {
    // Bt1[0,32M) P[32M,64M); phase B: out1[0,8M) W23t[8M,24M) b23@24M hbuf@24M+64K
    bf16_t* Bt1   = (bf16_t*)(ws);
    float*  P     = (float*)(ws + 32 * MB);
    bf16_t* out1  = (bf16_t*)(ws);
    bf16_t* W23t  = (bf16_t*)(ws + 8 * MB);
    float*  b23   = (float*)(ws + 24 * MB);
    bf16_t* hbuf  = (bf16_t*)(ws + 24 * MB + 65536);

    k_transpose<<<dim3(64, 64), 256, 0, stream>>>(fc1_w, comp, Bt1, 4096, 4096, 512);
    k_gemm_sk<4, 4, true><<<dim3(32, 8, 2), 256, 0, stream>>>(data, Bt1, P, 1024, 4096, 4096, 2048);
    k_reduce<2, false, false><<<4096, 256, 0, stream>>>(P, (size_t)1024 * 4096, fc1_b, nullptr, out1, 4096);
    hipMemsetAsync(b23, 0, 8192, stream);
    k_w23<<<dim3(32, 64), 256, 0, stream>>>(fc2_w, w3, fc2_b, W23t, b23);
    k_gemm_sk<4, 4, false><<<dim3(16, 8, 4), 256, 0, stream>>>(out1, W23t, P, 1024, 2048, 4096, 1024);
    k_reduce<4, true, true><<<2048, 256, 0, stream>>>(P, (size_t)1024 * 2048, b23, b3, hbuf, 2048);
    k_head<<<1024, 256, 0, stream>>>(hbuf, w4, b4, logits);
  }
}